// Round 4
// baseline (1392.755 us; speedup 1.0000x reference)
//
#include <hip/hip_runtime.h>

typedef unsigned short u16;
typedef __attribute__((ext_vector_type(8))) short short8;
typedef __attribute__((ext_vector_type(4))) float floatx4;

#define SOS 3
#define EOS 4
#define NEGV -10000.0f
#define LOG2E 1.442695041f
#define TWOLOG2E 2.885390082f

__device__ __forceinline__ float bf2f(u16 u) {
  union { unsigned int i; float f; } v; v.i = ((unsigned int)u) << 16; return v.f;
}
__device__ __forceinline__ u16 f2bf(float f) {
  union { float f; unsigned int i; } v; v.f = f;
  unsigned int r = (v.i + 0x7FFFu + ((v.i >> 16) & 1u)) >> 16;
  return (u16)r;
}
__device__ __forceinline__ void gload_lds16(const u16* g, u16* l) {
  __builtin_amdgcn_global_load_lds((const __attribute__((address_space(1))) void*)g,
                                   (__attribute__((address_space(3))) void*)l, 16, 0, 0);
}

// ---------------- gather: A[m=t*128+b][320] bf16 = embed[x[b][t]][k], zero-pad k>=300
__global__ __launch_bounds__(256) void gather_kernel(const float* __restrict__ embed,
                                                     const int* __restrict__ x,
                                                     u16* __restrict__ A) {
  int idx = blockIdx.x * 256 + threadIdx.x;   // 65536*40 chunks of 8
  int row = idx / 40;                          // m = t*128 + b
  int c8 = idx - row * 40;
  int col0 = c8 * 8;
  int b = row & 127, t = row >> 7;
  const float* src = embed + (size_t)x[b * 512 + t] * 300 + col0;
  short8 o;
  if (col0 + 8 <= 300) {
    float4 f0 = *(const float4*)(src);
    float4 f1 = *(const float4*)(src + 4);
    o[0] = (short)f2bf(f0.x); o[1] = (short)f2bf(f0.y);
    o[2] = (short)f2bf(f0.z); o[3] = (short)f2bf(f0.w);
    o[4] = (short)f2bf(f1.x); o[5] = (short)f2bf(f1.y);
    o[6] = (short)f2bf(f1.z); o[7] = (short)f2bf(f1.w);
  } else {
    #pragma unroll
    for (int e = 0; e < 8; ++e)
      o[e] = (col0 + e < 300) ? (short)f2bf(src[e]) : (short)0;
  }
  *(short8*)&A[(size_t)row * 320 + col0] = o;
}

// ---------------- pack W: Wp[1024][320] bf16 = [Wih_f; Wih_b], zero-pad
__global__ __launch_bounds__(256) void wpack_kernel(const float* __restrict__ Wf,
                                                    const float* __restrict__ Wb,
                                                    u16* __restrict__ Wp) {
  int idx = blockIdx.x * 256 + threadIdx.x;  // 1024*40
  int r = idx / 40;
  int c8 = idx - r * 40;
  int col0 = c8 * 8;
  const float* src = (r < 512) ? (Wf + (size_t)r * 300) : (Wb + (size_t)(r - 512) * 300);
  short8 o;
  #pragma unroll
  for (int e = 0; e < 8; ++e)
    o[e] = (col0 + e < 300) ? (short)f2bf(src[col0 + e]) : (short)0;
  *(short8*)&Wp[(size_t)r * 320 + col0] = o;
}

// ---------------- GEMM: G[65536][1024] bf16 = A @ Wp^T + bias, m97-style staging
__global__ __launch_bounds__(256) void gemm_kernel(const u16* __restrict__ A,
                                                   const u16* __restrict__ B,
                                                   const float* __restrict__ bf_,
                                                   const float* __restrict__ bb_,
                                                   u16* __restrict__ G) {
  __shared__ u16 At[128 * 32];
  __shared__ u16 Bt[128 * 32];
  const int n = blockIdx.x;
  const int xcd = n & 7, rr = n >> 3;
  const int bx = xcd * 64 + (rr >> 3);
  const int by = rr & 7;
  const int tid = threadIdx.x;
  const int lane = tid & 63;
  const int wave = tid >> 6;
  const int wr = wave >> 1, wc = wave & 1;
  const int arow0 = bx * 128;
  const int bcol0 = by * 128;
  floatx4 acc[4][4] = {};
  const int fq = lane >> 4;      // 0..3
  const int fr = lane & 15;      // 0..15
  const int sr = wave * 32 + (lane >> 2);   // staging row (q adds 16)
  const int sc = (lane & 3) * 8;            // staging col (u16)
  for (int k0 = 0; k0 < 320; k0 += 32) {
    #pragma unroll
    for (int q = 0; q < 2; ++q) {
      gload_lds16(&A[(size_t)(arow0 + sr + q * 16) * 320 + k0 + sc], &At[wave * 1024 + q * 512]);
      gload_lds16(&B[(size_t)(bcol0 + sr + q * 16) * 320 + k0 + sc], &Bt[wave * 1024 + q * 512]);
    }
    __syncthreads();
    short8 af[4], bfr[4];
    #pragma unroll
    for (int mi = 0; mi < 4; ++mi)
      af[mi] = *(const short8*)&At[(wr * 64 + mi * 16 + fr) * 32 + fq * 8];
    #pragma unroll
    for (int ni = 0; ni < 4; ++ni)
      bfr[ni] = *(const short8*)&Bt[(wc * 64 + ni * 16 + fr) * 32 + fq * 8];
    #pragma unroll
    for (int mi = 0; mi < 4; ++mi)
      #pragma unroll
      for (int ni = 0; ni < 4; ++ni)
        acc[mi][ni] = __builtin_amdgcn_mfma_f32_16x16x32_bf16(af[mi], bfr[ni], acc[mi][ni], 0, 0, 0);
    __syncthreads();
  }
  float biasv[4];
  #pragma unroll
  for (int ni = 0; ni < 4; ++ni) {
    int col = bcol0 + wc * 64 + ni * 16 + fr;
    biasv[ni] = (col < 512) ? bf_[col] : bb_[col - 512];
  }
  #pragma unroll
  for (int mi = 0; mi < 4; ++mi)
    #pragma unroll
    for (int ni = 0; ni < 4; ++ni)
      #pragma unroll
      for (int r = 0; r < 4; ++r) {
        int row = arow0 + wr * 64 + mi * 16 + fq * 4 + r;
        int col = bcol0 + wc * 64 + ni * 16 + fr;
        G[(size_t)row * 1024 + col] = f2bf(acc[mi][ni][r] + biasv[ni]);
      }
}

// ---------------- MFMA LSTM, dual-sequence interleave: WG = 1 dir x 32 batches
// (two groups of 16 sharing Whh fragments). 8 WGs = (dir 2) x (batch-quad 4).
// Wave w owns j-tile [16w,16w+16) per gate for BOTH groups -> 32 MFMAs/step as
// 8 independent 4-deep chains; two act blocks interleave on VALU/trans pipes.
__global__ __launch_bounds__(512, 2) void lstm_mfma_kernel(const u16* __restrict__ Gp,
                                                           const float* __restrict__ Whh_f,
                                                           const float* __restrict__ Whh_b,
                                                           u16* __restrict__ hs) {
  const int d  = blockIdx.x >> 2;
  const int b0 = (blockIdx.x & 3) * 32;
  const int tid = threadIdx.x;
  const int w    = tid >> 6;
  const int lane = tid & 63;
  const int fr = lane & 15;
  const int fq = lane >> 4;
  const float* Wd = d ? Whh_b : Whh_f;

  // A-operand fragments of Whh, resident all 512 steps: Wf[g][kk]
  short8 Wf[4][4];
  #pragma unroll
  for (int g = 0; g < 4; ++g)
    #pragma unroll
    for (int kk = 0; kk < 4; ++kk) {
      const float* src = Wd + (size_t)(g * 128 + 16 * w + fr) * 128 + fq * 8 + kk * 32;
      float4 x0 = *(const float4*)src;
      float4 x1 = *(const float4*)(src + 4);
      short8 o;
      o[0] = (short)f2bf(x0.x); o[1] = (short)f2bf(x0.y);
      o[2] = (short)f2bf(x0.z); o[3] = (short)f2bf(x0.w);
      o[4] = (short)f2bf(x1.x); o[5] = (short)f2bf(x1.y);
      o[6] = (short)f2bf(x1.z); o[7] = (short)f2bf(x1.w);
      Wf[g][kk] = o;
    }

  __shared__ __align__(16) u16 hbuf[2][2][16 * 136];  // [group][buf][b*136 + j]
  {
    u16* hz = &hbuf[0][0][0];
    for (int i = tid; i < 2 * 2 * 16 * 136; i += 512) hz[i] = 0;
  }
  __syncthreads();

  float cstA[4] = {0.f, 0.f, 0.f, 0.f};
  float cstB[4] = {0.f, 0.f, 0.f, 0.f};
  const int ts = d ? -1 : 1;
  const int t0 = d ? 511 : 0;
  const int laneoffA = (b0 + fr) * 1024 + d * 512 + 16 * w + fq * 4;
  const int laneoffB = laneoffA + 16 * 1024;
  const int hoff_r = fr * 136 + fq * 8;
  const int hoff_w = fr * 136 + 16 * w + fq * 4;
  u16* hsA = hs + (size_t)(b0 + fr) * 512 * 256 + d * 128 + 16 * w + fq * 4;
  u16* hsB = hsA + (size_t)16 * 512 * 256;

  uint2 gA0[4], gB0[4], gA1[4], gB1[4];
#define LOADG(GB_, TP_, LO_) { \
    const u16* p_ = Gp + (long long)(TP_) * 131072 + (LO_); \
    _Pragma("unroll") \
    for (int g_ = 0; g_ < 4; ++g_) (GB_)[g_] = *(const uint2*)(p_ + g_ * 128); \
  }
  LOADG(gA0, t0, laneoffA); LOADG(gB0, t0, laneoffB);
  LOADG(gA1, t0 + ts, laneoffA); LOADG(gB1, t0 + ts, laneoffB);

  u16* hrA = &hbuf[0][0][0]; u16* hwA = &hbuf[0][1][0];
  u16* hrB = &hbuf[1][0][0]; u16* hwB = &hbuf[1][1][0];

  auto ACT = [&](floatx4* acc, float* cst, u16* hwp, u16* hsb, int t) {
    float hv[4];
    #pragma unroll
    for (int i = 0; i < 4; ++i) {
      float i_ = acc[0][i], f_ = acc[1][i], g_ = acc[2][i], o_ = acc[3][i];
      float p  = __builtin_amdgcn_exp2f(fminf(fmaxf(g_ * TWOLOG2E, -100.f), 100.f)); // e^{2g}
      float qi = __builtin_amdgcn_exp2f(i_ * -LOG2E);
      float qf = __builtin_amdgcn_exp2f(f_ * -LOG2E);
      float D1 = (1.f + qi) * (p + 1.f);
      float qf1 = 1.f + qf;
      float num = cst[i] * D1 + (p - 1.f) * qf1;
      float cn = num * __builtin_amdgcn_rcpf(qf1 * D1);   // sig(f)*c + sig(i)*tanh(g)
      cst[i] = cn;
      float qo = __builtin_amdgcn_exp2f(o_ * -LOG2E);
      float v  = __builtin_amdgcn_exp2f(fminf(fmaxf(cn * TWOLOG2E, -100.f), 100.f)); // e^{2c}
      hv[i] = (v - 1.f) * __builtin_amdgcn_rcpf((1.f + qo) * (v + 1.f));
    }
    unsigned a0 = __builtin_bit_cast(unsigned, hv[0]) + 0x8000u;
    unsigned a1 = __builtin_bit_cast(unsigned, hv[1]) + 0x8000u;
    unsigned a2 = __builtin_bit_cast(unsigned, hv[2]) + 0x8000u;
    unsigned a3 = __builtin_bit_cast(unsigned, hv[3]) + 0x8000u;
    uint2 pk;
    pk.x = (a0 >> 16) | (a1 & 0xffff0000u);
    pk.y = (a2 >> 16) | (a3 & 0xffff0000u);
    *(uint2*)(hwp + hoff_w) = pk;                  // ds_write_b64
    *(uint2*)(hsb + (size_t)t * 256) = pk;         // global dwordx2, never drained
  };

  auto STEP2 = [&](uint2 (&GA)[4], uint2 (&GB)[4], int S, bool ISSUE) {
    const int t = d ? (511 - S) : S;
    short8 fA[4], fB[4];
    #pragma unroll
    for (int kk = 0; kk < 4; ++kk) {
      fA[kk] = *(const short8*)(hrA + hoff_r + kk * 32);
      fB[kk] = *(const short8*)(hrB + hoff_r + kk * 32);
    }
    floatx4 aA[4], aB[4];
    #pragma unroll
    for (int g = 0; g < 4; ++g) {
      floatx4 a, b;
      a[0] = __builtin_bit_cast(float, GA[g].x << 16);
      a[1] = __builtin_bit_cast(float, GA[g].x & 0xffff0000u);
      a[2] = __builtin_bit_cast(float, GA[g].y << 16);
      a[3] = __builtin_bit_cast(float, GA[g].y & 0xffff0000u);
      b[0] = __builtin_bit_cast(float, GB[g].x << 16);
      b[1] = __builtin_bit_cast(float, GB[g].x & 0xffff0000u);
      b[2] = __builtin_bit_cast(float, GB[g].y << 16);
      b[3] = __builtin_bit_cast(float, GB[g].y & 0xffff0000u);
      aA[g] = a; aB[g] = b;
    }
    #pragma unroll
    for (int kk = 0; kk < 4; ++kk) {
      aA[0] = __builtin_amdgcn_mfma_f32_16x16x32_bf16(Wf[0][kk], fA[kk], aA[0], 0, 0, 0);
      aB[0] = __builtin_amdgcn_mfma_f32_16x16x32_bf16(Wf[0][kk], fB[kk], aB[0], 0, 0, 0);
      aA[1] = __builtin_amdgcn_mfma_f32_16x16x32_bf16(Wf[1][kk], fA[kk], aA[1], 0, 0, 0);
      aB[1] = __builtin_amdgcn_mfma_f32_16x16x32_bf16(Wf[1][kk], fB[kk], aB[1], 0, 0, 0);
      aA[2] = __builtin_amdgcn_mfma_f32_16x16x32_bf16(Wf[2][kk], fA[kk], aA[2], 0, 0, 0);
      aB[2] = __builtin_amdgcn_mfma_f32_16x16x32_bf16(Wf[2][kk], fB[kk], aB[2], 0, 0, 0);
      aA[3] = __builtin_amdgcn_mfma_f32_16x16x32_bf16(Wf[3][kk], fA[kk], aA[3], 0, 0, 0);
      aB[3] = __builtin_amdgcn_mfma_f32_16x16x32_bf16(Wf[3][kk], fB[kk], aB[3], 0, 0, 0);
    }
    if (ISSUE) { LOADG(GA, t + 2 * ts, laneoffA); LOADG(GB, t + 2 * ts, laneoffB); }
    ACT(aA, cstA, hwA, hsA, t);
    ACT(aB, cstB, hwB, hsB, t);
    __builtin_amdgcn_sched_barrier(0);
    asm volatile("s_waitcnt lgkmcnt(0)");
    __builtin_amdgcn_sched_barrier(0);
    __builtin_amdgcn_s_barrier();
    __builtin_amdgcn_sched_barrier(0);
    u16* tp;
    tp = hrA; hrA = hwA; hwA = tp;
    tp = hrB; hrB = hwB; hwB = tp;
  };

  #pragma unroll 1
  for (int s = 0; s < 512; s += 2) {
    STEP2(gA0, gB0, s, s + 2 < 512);
    STEP2(gA1, gB1, s + 1, s + 3 < 512);
  }
#undef LOADG
}

// ---------------- emissions: y[65536][12] = hs(bf16)[65536][256] @ Wout^T + bout
__global__ __launch_bounds__(256) void emis_kernel(const u16* __restrict__ hs,
                                                   const float* __restrict__ Wout,
                                                   const float* __restrict__ bout,
                                                   float* __restrict__ y) {
  __shared__ float Ws[12 * 256];
  __shared__ float bs[12];
  const int tid = threadIdx.x;
  for (int i = tid; i < 12 * 256; i += 256) Ws[i] = Wout[i];
  if (tid < 12) bs[tid] = bout[tid];
  __syncthreads();
  const int wave = tid >> 6, lane = tid & 63;
  const size_t m = (size_t)blockIdx.x * 4 + wave;
  uint2 hv = *(const uint2*)&hs[m * 256 + lane * 4];
  float h0 = __builtin_bit_cast(float, hv.x << 16);
  float h1 = __builtin_bit_cast(float, hv.x & 0xffff0000u);
  float h2 = __builtin_bit_cast(float, hv.y << 16);
  float h3 = __builtin_bit_cast(float, hv.y & 0xffff0000u);
  float p[12];
  #pragma unroll
  for (int tg = 0; tg < 12; ++tg) {
    const float* wv = &Ws[tg * 256 + lane * 4];
    p[tg] = h0 * wv[0] + h1 * wv[1] + h2 * wv[2] + h3 * wv[3];
  }
  #pragma unroll
  for (int off = 32; off; off >>= 1)
    #pragma unroll
    for (int tg = 0; tg < 12; ++tg)
      p[tg] += __shfl_xor(p[tg], off);
  if (lane == 0) {
    #pragma unroll
    for (int tg = 0; tg < 12; ++tg)
      y[m * 12 + tg] = p[tg] + bs[tg];
  }
}

// ---------------- CRF: forward Z + gold score, one wave per batch.
// State kept normalized to lane 0 (z[0] == 0 after step 1) -> no per-step max
// reduce; running base accumulated from lane 0's log-sum. SOS row -> -inf exactly.
__global__ __launch_bounds__(64) void crf_kernel(const float* __restrict__ y,
                                                 const int* __restrict__ y0,
                                                 const float* __restrict__ trans,
                                                 float* __restrict__ out) {
  const int b = blockIdx.x;
  const int lane = threadIdx.x;
  __shared__ float trs[144];
  for (int i = lane; i < 144; i += 64) trs[i] = trans[i];
  __syncthreads();
  float etr[12];
  #pragma unroll
  for (int jj = 0; jj < 12; ++jj) etr[jj] = 0.f;
  float z = NEGV, treos = 0.f;
  if (lane < 12) {
    #pragma unroll
    for (int jj = 0; jj < 12; ++jj) etr[jj] = __expf(trs[lane * 12 + jj]);
    z = (lane == SOS) ? 0.f : NEGV;
    treos = trs[EOS * 12 + lane];
  }
  float base = 0.f;
  const float* yb = y + (size_t)b * 512 * 12;
  float e0 = (lane < 12) ? yb[lane] : 0.f;
  float e1 = (lane < 12) ? yb[12 + lane] : 0.f;
  for (int t = 0; t < 512; ++t) {
    float emit = e0;
    e0 = e1;
    if (t + 2 < 512 && lane < 12) e1 = yb[(t + 2) * 12 + lane];
    float zj[12];
    #pragma unroll
    for (int jj = 0; jj < 12; ++jj) zj[jj] = __shfl(z, jj);
    float l = 0.f;
    if (lane < 12) {
      float ex[12];
      #pragma unroll
      for (int jj = 0; jj < 12; ++jj) ex[jj] = __expf(zj[jj]) * etr[jj];
      float sum = (((ex[0] + ex[1]) + (ex[2] + ex[3])) + ((ex[4] + ex[5]) + (ex[6] + ex[7])))
                + ((ex[8] + ex[9]) + (ex[10] + ex[11]));
      l = __logf(sum) + emit;
    }
    float l0 = __shfl(l, 0);
    z = l - l0;            // lane 0 -> exactly 0
    base += l0;
  }
  float v = (lane < 12) ? z + treos : -INFINITY;
  float M2 = v;
  #pragma unroll
  for (int off = 32; off; off >>= 1) M2 = fmaxf(M2, __shfl_xor(M2, off));
  float e = __expf(v - M2);
  #pragma unroll
  for (int off = 32; off; off >>= 1) e += __shfl_xor(e, off);
  const float Z = base + M2 + __logf(e);
  const int* y0b = y0 + (size_t)b * 512;
  float acc = 0.f;
  for (int t = lane; t < 512; t += 64) {
    int cur = y0b[t];
    int prev = t ? y0b[t - 1] : SOS;
    acc += yb[t * 12 + cur] + trs[cur * 12 + prev];
  }
  #pragma unroll
  for (int off = 32; off; off >>= 1) acc += __shfl_xor(acc, off);
  if (lane == 0) {
    float gold = acc + trs[EOS * 12 + y0b[511]];
    out[b] = Z - gold;
  }
}

extern "C" void kernel_launch(void* const* d_in, const int* in_sizes, int n_in,
                              void* d_out, int out_size, void* d_ws, size_t ws_size,
                              hipStream_t stream) {
  (void)in_sizes; (void)n_in; (void)out_size; (void)ws_size;
  const int*   x     = (const int*)d_in[0];
  const int*   y0    = (const int*)d_in[1];
  const float* embed = (const float*)d_in[2];
  const float* Wih_f = (const float*)d_in[3];
  const float* Whh_f = (const float*)d_in[4];
  const float* b_f   = (const float*)d_in[5];
  const float* Wih_b = (const float*)d_in[6];
  const float* Whh_b = (const float*)d_in[7];
  const float* b_b   = (const float*)d_in[8];
  const float* Wout  = (const float*)d_in[9];
  const float* bout  = (const float*)d_in[10];
  const float* trans = (const float*)d_in[11];
  float* out = (float*)d_out;

  char* ws = (char*)d_ws;
  u16*   A  = (u16*)(ws);                      // 65536*320 bf16  = 41,943,040 B
  u16*   Wp = (u16*)(ws + 41943040);           // 1024*320  bf16  =    655,360 B
  u16*   G  = (u16*)(ws + 42598400);           // 65536*1024 bf16 = 134,217,728 B
  u16*   hs = (u16*)(ws + 176816128);          // 65536*256 bf16  =  33,554,432 B
  float* yy = (float*)(ws + 210370560);        // 65536*12  f32   =   3,145,728 B

  gather_kernel<<<10240, 256, 0, stream>>>(embed, x, A);
  wpack_kernel<<<160, 256, 0, stream>>>(Wih_f, Wih_b, Wp);
  gemm_kernel<<<4096, 256, 0, stream>>>(A, Wp, b_f, b_b, G);
  lstm_mfma_kernel<<<8, 512, 0, stream>>>(G, Whh_f, Whh_b, hs);
  emis_kernel<<<16384, 256, 0, stream>>>(hs, Wout, bout, yy);
  crf_kernel<<<128, 64, 0, stream>>>(yy, y0, trans, out);
}

// Round 5
// 816.110 us; speedup vs baseline: 1.7066x; 1.7066x over previous
//
#include <hip/hip_runtime.h>

typedef unsigned short u16;
typedef __attribute__((ext_vector_type(8))) short short8;
typedef __attribute__((ext_vector_type(4))) float floatx4;

#define SOS 3
#define EOS 4
#define NEGV -10000.0f
#define LOG2E 1.442695041f
#define TWOLOG2E 2.885390082f

__device__ __forceinline__ float bf2f(u16 u) {
  union { unsigned int i; float f; } v; v.i = ((unsigned int)u) << 16; return v.f;
}
__device__ __forceinline__ u16 f2bf(float f) {
  union { float f; unsigned int i; } v; v.f = f;
  unsigned int r = (v.i + 0x7FFFu + ((v.i >> 16) & 1u)) >> 16;
  return (u16)r;
}
__device__ __forceinline__ void gload_lds16(const u16* g, u16* l) {
  __builtin_amdgcn_global_load_lds((const __attribute__((address_space(1))) void*)g,
                                   (__attribute__((address_space(3))) void*)l, 16, 0, 0);
}

// ---------------- gather: A[m=t*128+b][320] bf16 = embed[x[b][t]][k], zero-pad k>=300
__global__ __launch_bounds__(256) void gather_kernel(const float* __restrict__ embed,
                                                     const int* __restrict__ x,
                                                     u16* __restrict__ A) {
  int idx = blockIdx.x * 256 + threadIdx.x;
  int row = idx / 40;
  int c8 = idx - row * 40;
  int col0 = c8 * 8;
  int b = row & 127, t = row >> 7;
  const float* src = embed + (size_t)x[b * 512 + t] * 300 + col0;
  short8 o;
  if (col0 + 8 <= 300) {
    float4 f0 = *(const float4*)(src);
    float4 f1 = *(const float4*)(src + 4);
    o[0] = (short)f2bf(f0.x); o[1] = (short)f2bf(f0.y);
    o[2] = (short)f2bf(f0.z); o[3] = (short)f2bf(f0.w);
    o[4] = (short)f2bf(f1.x); o[5] = (short)f2bf(f1.y);
    o[6] = (short)f2bf(f1.z); o[7] = (short)f2bf(f1.w);
  } else {
    #pragma unroll
    for (int e = 0; e < 8; ++e)
      o[e] = (col0 + e < 300) ? (short)f2bf(src[e]) : (short)0;
  }
  *(short8*)&A[(size_t)row * 320 + col0] = o;
}

// ---------------- pack W: Wp[1024][320] bf16 = [Wih_f; Wih_b], zero-pad
__global__ __launch_bounds__(256) void wpack_kernel(const float* __restrict__ Wf,
                                                    const float* __restrict__ Wb,
                                                    u16* __restrict__ Wp) {
  int idx = blockIdx.x * 256 + threadIdx.x;
  int r = idx / 40;
  int c8 = idx - r * 40;
  int col0 = c8 * 8;
  const float* src = (r < 512) ? (Wf + (size_t)r * 300) : (Wb + (size_t)(r - 512) * 300);
  short8 o;
  #pragma unroll
  for (int e = 0; e < 8; ++e)
    o[e] = (col0 + e < 300) ? (short)f2bf(src[col0 + e]) : (short)0;
  *(short8*)&Wp[(size_t)r * 320 + col0] = o;
}

// ---------------- GEMM: G[65536][1024] = A @ Wp^T + bias (OT = f32 or bf16)
template <typename OT>
__global__ __launch_bounds__(256) void gemm_kernel(const u16* __restrict__ A,
                                                   const u16* __restrict__ B,
                                                   const float* __restrict__ bf_,
                                                   const float* __restrict__ bb_,
                                                   OT* __restrict__ G) {
  __shared__ u16 At[128 * 32];
  __shared__ u16 Bt[128 * 32];
  const int n = blockIdx.x;
  const int xcd = n & 7, rr = n >> 3;
  const int bx = xcd * 64 + (rr >> 3);
  const int by = rr & 7;
  const int tid = threadIdx.x;
  const int lane = tid & 63;
  const int wave = tid >> 6;
  const int wr = wave >> 1, wc = wave & 1;
  const int arow0 = bx * 128;
  const int bcol0 = by * 128;
  floatx4 acc[4][4] = {};
  const int fq = lane >> 4;
  const int fr = lane & 15;
  const int sr = wave * 32 + (lane >> 2);
  const int sc = (lane & 3) * 8;
  for (int k0 = 0; k0 < 320; k0 += 32) {
    #pragma unroll
    for (int q = 0; q < 2; ++q) {
      gload_lds16(&A[(size_t)(arow0 + sr + q * 16) * 320 + k0 + sc], &At[wave * 1024 + q * 512]);
      gload_lds16(&B[(size_t)(bcol0 + sr + q * 16) * 320 + k0 + sc], &Bt[wave * 1024 + q * 512]);
    }
    __syncthreads();
    short8 af[4], bfr[4];
    #pragma unroll
    for (int mi = 0; mi < 4; ++mi)
      af[mi] = *(const short8*)&At[(wr * 64 + mi * 16 + fr) * 32 + fq * 8];
    #pragma unroll
    for (int ni = 0; ni < 4; ++ni)
      bfr[ni] = *(const short8*)&Bt[(wc * 64 + ni * 16 + fr) * 32 + fq * 8];
    #pragma unroll
    for (int mi = 0; mi < 4; ++mi)
      #pragma unroll
      for (int ni = 0; ni < 4; ++ni)
        acc[mi][ni] = __builtin_amdgcn_mfma_f32_16x16x32_bf16(af[mi], bfr[ni], acc[mi][ni], 0, 0, 0);
    __syncthreads();
  }
  float biasv[4];
  #pragma unroll
  for (int ni = 0; ni < 4; ++ni) {
    int col = bcol0 + wc * 64 + ni * 16 + fr;
    biasv[ni] = (col < 512) ? bf_[col] : bb_[col - 512];
  }
  #pragma unroll
  for (int mi = 0; mi < 4; ++mi)
    #pragma unroll
    for (int ni = 0; ni < 4; ++ni)
      #pragma unroll
      for (int r = 0; r < 4; ++r) {
        int row = arow0 + wr * 64 + mi * 16 + fq * 4 + r;
        int col = bcol0 + wc * 64 + ni * 16 + fr;
        float v = acc[mi][ni][r] + biasv[ni];
        if constexpr (__is_same(OT, float)) G[(size_t)row * 1024 + col] = v;
        else                                G[(size_t)row * 1024 + col] = f2bf(v);
      }
}

// ---------------- MFMA LSTM, swapped operands D[j][b], lean straight-line body.
// 16 WGs = (dir 2) x (batch-group 8 of 16). G dtype templated (f32 when ws allows).
template <typename GT> struct graw_t;
template <> struct graw_t<float> { using T = float4; };
template <> struct graw_t<u16>   { using T = uint2; };

__device__ __forceinline__ floatx4 g_unpk(float4 v) {
  floatx4 a; a[0] = v.x; a[1] = v.y; a[2] = v.z; a[3] = v.w; return a;
}
__device__ __forceinline__ floatx4 g_unpk(uint2 v) {
  floatx4 a;
  a[0] = __builtin_bit_cast(float, v.x << 16);
  a[1] = __builtin_bit_cast(float, v.x & 0xffff0000u);
  a[2] = __builtin_bit_cast(float, v.y << 16);
  a[3] = __builtin_bit_cast(float, v.y & 0xffff0000u);
  return a;
}

template <typename GT>
__device__ __forceinline__ void lstm_seq(const GT* __restrict__ Gp,
                                         const float* __restrict__ Wd,
                                         u16* __restrict__ hs,
                                         int d, int b0, int tid) {
  const int w    = tid >> 6;
  const int lane = tid & 63;
  const int fr = lane & 15;
  const int fq = lane >> 4;
  using RAW = typename graw_t<GT>::T;

  // A-operand fragments of Whh, resident all 512 steps
  short8 Wfr[4][4];
  #pragma unroll
  for (int g = 0; g < 4; ++g)
    #pragma unroll
    for (int kk = 0; kk < 4; ++kk) {
      const float* src = Wd + (size_t)(g * 128 + 16 * w + fr) * 128 + fq * 8 + kk * 32;
      float4 x0 = *(const float4*)src;
      float4 x1 = *(const float4*)(src + 4);
      short8 o;
      o[0] = (short)f2bf(x0.x); o[1] = (short)f2bf(x0.y);
      o[2] = (short)f2bf(x0.z); o[3] = (short)f2bf(x0.w);
      o[4] = (short)f2bf(x1.x); o[5] = (short)f2bf(x1.y);
      o[6] = (short)f2bf(x1.z); o[7] = (short)f2bf(x1.w);
      Wfr[g][kk] = o;
    }

  __shared__ __align__(16) u16 hbuf[2][16 * 136];
  {
    u16* hz = &hbuf[0][0];
    for (int i = tid; i < 2 * 16 * 136; i += 512) hz[i] = 0;
  }
  __syncthreads();

  float cst[4] = {0.f, 0.f, 0.f, 0.f};
  const int ts = d ? -1 : 1;
  const int t0 = d ? 511 : 0;
  const long long RS = 131072;                      // elements per t-row of G
  const int laneoff = (b0 + fr) * 1024 + d * 512 + 16 * w + fq * 4;
  const int hoff_r = fr * 136 + fq * 8;
  const int hoff_w = fr * 136 + 16 * w + fq * 4;
  const long long gstep = (long long)ts * RS;
  const long long hstep = (long long)ts * 256;
  const GT* gld = Gp + (long long)t0 * RS + laneoff; // load cursor
  u16* hsp = hs + (size_t)(b0 + fr) * 131072 + (long long)t0 * 256 + d * 128 + 16 * w + fq * 4;

  RAW gA[4], gB[4], gC[4];
#define LOADRAW(GB_) { \
    _Pragma("unroll") \
    for (int g_ = 0; g_ < 4; ++g_) (GB_)[g_] = *(const RAW*)(gld + g_ * 128); \
    gld += gstep; \
  }
  LOADRAW(gA); LOADRAW(gB); LOADRAW(gC);

  u16* hr = &hbuf[0][0];
  u16* hw = &hbuf[1][0];

#define STEPB(GB_, PF_) { \
    short8 f0 = *(const short8*)(hr + hoff_r); \
    short8 f1 = *(const short8*)(hr + hoff_r + 32); \
    short8 f2 = *(const short8*)(hr + hoff_r + 64); \
    short8 f3 = *(const short8*)(hr + hoff_r + 96); \
    floatx4 a0 = g_unpk(GB_[0]); \
    floatx4 a1 = g_unpk(GB_[1]); \
    floatx4 a2 = g_unpk(GB_[2]); \
    floatx4 a3 = g_unpk(GB_[3]); \
    a0 = __builtin_amdgcn_mfma_f32_16x16x32_bf16(Wfr[0][0], f0, a0, 0, 0, 0); \
    a1 = __builtin_amdgcn_mfma_f32_16x16x32_bf16(Wfr[1][0], f0, a1, 0, 0, 0); \
    a2 = __builtin_amdgcn_mfma_f32_16x16x32_bf16(Wfr[2][0], f0, a2, 0, 0, 0); \
    a3 = __builtin_amdgcn_mfma_f32_16x16x32_bf16(Wfr[3][0], f0, a3, 0, 0, 0); \
    a0 = __builtin_amdgcn_mfma_f32_16x16x32_bf16(Wfr[0][1], f1, a0, 0, 0, 0); \
    a1 = __builtin_amdgcn_mfma_f32_16x16x32_bf16(Wfr[1][1], f1, a1, 0, 0, 0); \
    a2 = __builtin_amdgcn_mfma_f32_16x16x32_bf16(Wfr[2][1], f1, a2, 0, 0, 0); \
    a3 = __builtin_amdgcn_mfma_f32_16x16x32_bf16(Wfr[3][1], f1, a3, 0, 0, 0); \
    a0 = __builtin_amdgcn_mfma_f32_16x16x32_bf16(Wfr[0][2], f2, a0, 0, 0, 0); \
    a1 = __builtin_amdgcn_mfma_f32_16x16x32_bf16(Wfr[1][2], f2, a1, 0, 0, 0); \
    a2 = __builtin_amdgcn_mfma_f32_16x16x32_bf16(Wfr[2][2], f2, a2, 0, 0, 0); \
    a3 = __builtin_amdgcn_mfma_f32_16x16x32_bf16(Wfr[3][2], f2, a3, 0, 0, 0); \
    a0 = __builtin_amdgcn_mfma_f32_16x16x32_bf16(Wfr[0][3], f3, a0, 0, 0, 0); \
    a1 = __builtin_amdgcn_mfma_f32_16x16x32_bf16(Wfr[1][3], f3, a1, 0, 0, 0); \
    a2 = __builtin_amdgcn_mfma_f32_16x16x32_bf16(Wfr[2][3], f3, a2, 0, 0, 0); \
    a3 = __builtin_amdgcn_mfma_f32_16x16x32_bf16(Wfr[3][3], f3, a3, 0, 0, 0); \
    if (PF_) LOADRAW(GB_); \
    float hv[4]; \
    _Pragma("unroll") \
    for (int i = 0; i < 4; ++i) { \
      float i_ = a0[i], f_ = a1[i], g_ = a2[i], o_ = a3[i]; \
      float p  = __builtin_amdgcn_exp2f(__builtin_amdgcn_fmed3f(g_ * TWOLOG2E, -40.f, 40.f)); \
      float qi = __builtin_amdgcn_exp2f(__builtin_amdgcn_fmed3f(i_ * -LOG2E, -40.f, 40.f)); \
      float qf = __builtin_amdgcn_exp2f(__builtin_amdgcn_fmed3f(f_ * -LOG2E, -40.f, 40.f)); \
      float qo = __builtin_amdgcn_exp2f(__builtin_amdgcn_fmed3f(o_ * -LOG2E, -40.f, 40.f)); \
      float D1 = (1.f + qi) * (p + 1.f); \
      float qf1 = 1.f + qf; \
      float num = cst[i] * (qf1 * D1) * 0.f + cst[i] * D1 + (p - 1.f) * qf1; \
      float cn = num * __builtin_amdgcn_rcpf(qf1 * D1); \
      cst[i] = cn; \
      float v = __builtin_amdgcn_exp2f(__builtin_amdgcn_fmed3f(cn * TWOLOG2E, -40.f, 40.f)); \
      hv[i] = (v - 1.f) * __builtin_amdgcn_rcpf((1.f + qo) * (v + 1.f)); \
    } \
    unsigned px, py; \
    asm("v_cvt_pk_bf16_f32 %0, %1, %2" : "=v"(px) : "v"(hv[0]), "v"(hv[1])); \
    asm("v_cvt_pk_bf16_f32 %0, %1, %2" : "=v"(py) : "v"(hv[2]), "v"(hv[3])); \
    uint2 pk; pk.x = px; pk.y = py; \
    *(uint2*)(hw + hoff_w) = pk; \
    *(uint2*)hsp = pk; \
    hsp += hstep; \
    __builtin_amdgcn_sched_barrier(0); \
    asm volatile("s_waitcnt lgkmcnt(0)"); \
    __builtin_amdgcn_sched_barrier(0); \
    __builtin_amdgcn_s_barrier(); \
    __builtin_amdgcn_sched_barrier(0); \
    u16* tp_ = hr; hr = hw; hw = tp_; \
  }

  #pragma unroll 1
  for (int s = 0; s < 510; s += 3) {
    STEPB(gA, true);
    STEPB(gB, true);
    STEPB(gC, true);
  }
  STEPB(gA, false);
  STEPB(gB, false);
#undef STEPB
#undef LOADRAW
}

__global__ __launch_bounds__(512, 2) void lstm_f32(const float* __restrict__ G,
                                                   const float* __restrict__ Wf,
                                                   const float* __restrict__ Wb,
                                                   u16* __restrict__ hs) {
  const int d = blockIdx.x >> 3;
  const int b0 = (blockIdx.x & 7) * 16;
  lstm_seq<float>(G, d ? Wb : Wf, hs, d, b0, threadIdx.x);
}
__global__ __launch_bounds__(512, 2) void lstm_bf16(const u16* __restrict__ G,
                                                    const float* __restrict__ Wf,
                                                    const float* __restrict__ Wb,
                                                    u16* __restrict__ hs) {
  const int d = blockIdx.x >> 3;
  const int b0 = (blockIdx.x & 7) * 16;
  lstm_seq<u16>(G, d ? Wb : Wf, hs, d, b0, threadIdx.x);
}

// ---------------- emissions: y[65536][12] = hs(bf16)[65536][256] @ Wout^T + bout
__global__ __launch_bounds__(256) void emis_kernel(const u16* __restrict__ hs,
                                                   const float* __restrict__ Wout,
                                                   const float* __restrict__ bout,
                                                   float* __restrict__ y) {
  __shared__ float Ws[12 * 256];
  __shared__ float bs[12];
  const int tid = threadIdx.x;
  for (int i = tid; i < 12 * 256; i += 256) Ws[i] = Wout[i];
  if (tid < 12) bs[tid] = bout[tid];
  __syncthreads();
  const int wave = tid >> 6, lane = tid & 63;
  const size_t m = (size_t)blockIdx.x * 4 + wave;
  uint2 hv = *(const uint2*)&hs[m * 256 + lane * 4];
  float h0 = __builtin_bit_cast(float, hv.x << 16);
  float h1 = __builtin_bit_cast(float, hv.x & 0xffff0000u);
  float h2 = __builtin_bit_cast(float, hv.y << 16);
  float h3 = __builtin_bit_cast(float, hv.y & 0xffff0000u);
  float p[12];
  #pragma unroll
  for (int tg = 0; tg < 12; ++tg) {
    const float* wv = &Ws[tg * 256 + lane * 4];
    p[tg] = h0 * wv[0] + h1 * wv[1] + h2 * wv[2] + h3 * wv[3];
  }
  #pragma unroll
  for (int off = 32; off; off >>= 1)
    #pragma unroll
    for (int tg = 0; tg < 12; ++tg)
      p[tg] += __shfl_xor(p[tg], off);
  if (lane == 0) {
    #pragma unroll
    for (int tg = 0; tg < 12; ++tg)
      y[m * 12 + tg] = p[tg] + bs[tg];
  }
}

// ---------------- CRF: forward Z + gold score, one wave per batch (lane-0 normalized)
__global__ __launch_bounds__(64) void crf_kernel(const float* __restrict__ y,
                                                 const int* __restrict__ y0,
                                                 const float* __restrict__ trans,
                                                 float* __restrict__ out) {
  const int b = blockIdx.x;
  const int lane = threadIdx.x;
  __shared__ float trs[144];
  for (int i = lane; i < 144; i += 64) trs[i] = trans[i];
  __syncthreads();
  float etr[12];
  #pragma unroll
  for (int jj = 0; jj < 12; ++jj) etr[jj] = 0.f;
  float z = NEGV, treos = 0.f;
  if (lane < 12) {
    #pragma unroll
    for (int jj = 0; jj < 12; ++jj) etr[jj] = __expf(trs[lane * 12 + jj]);
    z = (lane == SOS) ? 0.f : NEGV;
    treos = trs[EOS * 12 + lane];
  }
  float base = 0.f;
  const float* yb = y + (size_t)b * 512 * 12;
  float e0 = (lane < 12) ? yb[lane] : 0.f;
  float e1 = (lane < 12) ? yb[12 + lane] : 0.f;
  for (int t = 0; t < 512; ++t) {
    float emit = e0;
    e0 = e1;
    if (t + 2 < 512 && lane < 12) e1 = yb[(t + 2) * 12 + lane];
    float zj[12];
    #pragma unroll
    for (int jj = 0; jj < 12; ++jj) zj[jj] = __shfl(z, jj);
    float l = 0.f;
    if (lane < 12) {
      float ex[12];
      #pragma unroll
      for (int jj = 0; jj < 12; ++jj) ex[jj] = __expf(zj[jj]) * etr[jj];
      float sum = (((ex[0] + ex[1]) + (ex[2] + ex[3])) + ((ex[4] + ex[5]) + (ex[6] + ex[7])))
                + ((ex[8] + ex[9]) + (ex[10] + ex[11]));
      l = __logf(sum) + emit;
    }
    float l0 = __shfl(l, 0);
    z = l - l0;
    base += l0;
  }
  float v = (lane < 12) ? z + treos : -INFINITY;
  float M2 = v;
  #pragma unroll
  for (int off = 32; off; off >>= 1) M2 = fmaxf(M2, __shfl_xor(M2, off));
  float e = __expf(v - M2);
  #pragma unroll
  for (int off = 32; off; off >>= 1) e += __shfl_xor(e, off);
  const float Z = base + M2 + __logf(e);
  const int* y0b = y0 + (size_t)b * 512;
  float acc = 0.f;
  for (int t = lane; t < 512; t += 64) {
    int cur = y0b[t];
    int prev = t ? y0b[t - 1] : SOS;
    acc += yb[t * 12 + cur] + trs[cur * 12 + prev];
  }
  #pragma unroll
  for (int off = 32; off; off >>= 1) acc += __shfl_xor(acc, off);
  if (lane == 0) {
    float gold = acc + trs[EOS * 12 + y0b[511]];
    out[b] = Z - gold;
  }
}

extern "C" void kernel_launch(void* const* d_in, const int* in_sizes, int n_in,
                              void* d_out, int out_size, void* d_ws, size_t ws_size,
                              hipStream_t stream) {
  (void)in_sizes; (void)n_in; (void)out_size;
  const int*   x     = (const int*)d_in[0];
  const int*   y0    = (const int*)d_in[1];
  const float* embed = (const float*)d_in[2];
  const float* Wih_f = (const float*)d_in[3];
  const float* Whh_f = (const float*)d_in[4];
  const float* b_f   = (const float*)d_in[5];
  const float* Wih_b = (const float*)d_in[6];
  const float* Whh_b = (const float*)d_in[7];
  const float* b_b   = (const float*)d_in[8];
  const float* Wout  = (const float*)d_in[9];
  const float* bout  = (const float*)d_in[10];
  const float* trans = (const float*)d_in[11];
  float* out = (float*)d_out;

  char* ws = (char*)d_ws;
  const bool useF32 = ws_size >= (size_t)312606720;

  u16* A  = (u16*)(ws);                 // 65536*320 bf16 = 41,943,040 B
  u16* Wp = (u16*)(ws + 41943040);      // 1024*320 bf16  =    655,360 B

  gather_kernel<<<10240, 256, 0, stream>>>(embed, x, A);
  wpack_kernel<<<160, 256, 0, stream>>>(Wih_f, Wih_b, Wp);

  if (useF32) {
    // f32-G layout: G@42,598,400 (515 rows x 131072 x 4B incl. prefetch slack),
    // hs/yy overlap the dead A region after GEMM.
    float* G  = (float*)(ws + 42598400);
    u16*   hs = (u16*)(ws);                    // 33,554,432 B (A is dead post-GEMM)
    float* yy = (float*)(ws + 33554432);       //  3,145,728 B
    gemm_kernel<float><<<4096, 256, 0, stream>>>(A, Wp, b_f, b_b, G);
    lstm_f32<<<16, 512, 0, stream>>>(G, Whh_f, Whh_b, hs);
    emis_kernel<<<16384, 256, 0, stream>>>(hs, Wout, bout, yy);
    crf_kernel<<<128, 64, 0, stream>>>(yy, y0, trans, out);
  } else {
    u16*   G  = (u16*)(ws + 42598400);         // 134,217,728 B
    u16*   hs = (u16*)(ws + 176816128);        //  33,554,432 B
    float* yy = (float*)(ws + 210370560);      //   3,145,728 B
    gemm_kernel<u16><<<4096, 256, 0, stream>>>(A, Wp, b_f, b_b, G);
    lstm_bf16<<<16, 512, 0, stream>>>(G, Whh_f, Whh_b, hs);
    emis_kernel<<<16384, 256, 0, stream>>>(hs, Wout, bout, yy);
    crf_kernel<<<128, 64, 0, stream>>>(yy, y0, trans, out);
  }
}

// Round 6
// 679.821 us; speedup vs baseline: 2.0487x; 1.2005x over previous
//
#include <hip/hip_runtime.h>

typedef unsigned short u16;
typedef __attribute__((ext_vector_type(8))) short short8;
typedef __attribute__((ext_vector_type(4))) float floatx4;

#define SOS 3
#define EOS 4
#define NEGV -10000.0f
#define LOG2E 1.442695041f
#define TWOLOG2E 2.885390082f

__device__ __forceinline__ u16 f2bf(float f) {
  union { float f; unsigned int i; } v; v.f = f;
  unsigned int r = (v.i + 0x7FFFu + ((v.i >> 16) & 1u)) >> 16;
  return (u16)r;
}
__device__ __forceinline__ void gload_lds16(const u16* g, u16* l) {
  __builtin_amdgcn_global_load_lds((const __attribute__((address_space(1))) void*)g,
                                   (__attribute__((address_space(3))) void*)l, 16, 0, 0);
}

// ---------------- gather: A[m=t*128+b][320] bf16 = embed[x[b][t]][k], zero-pad k>=300
__global__ __launch_bounds__(256) void gather_kernel(const float* __restrict__ embed,
                                                     const int* __restrict__ x,
                                                     u16* __restrict__ A) {
  int idx = blockIdx.x * 256 + threadIdx.x;
  int row = idx / 40;
  int c8 = idx - row * 40;
  int col0 = c8 * 8;
  int b = row & 127, t = row >> 7;
  const float* src = embed + (size_t)x[b * 512 + t] * 300 + col0;
  short8 o;
  if (col0 + 8 <= 300) {
    float4 f0 = *(const float4*)(src);
    float4 f1 = *(const float4*)(src + 4);
    o[0] = (short)f2bf(f0.x); o[1] = (short)f2bf(f0.y);
    o[2] = (short)f2bf(f0.z); o[3] = (short)f2bf(f0.w);
    o[4] = (short)f2bf(f1.x); o[5] = (short)f2bf(f1.y);
    o[6] = (short)f2bf(f1.z); o[7] = (short)f2bf(f1.w);
  } else {
    #pragma unroll
    for (int e = 0; e < 8; ++e)
      o[e] = (col0 + e < 300) ? (short)f2bf(src[e]) : (short)0;
  }
  *(short8*)&A[(size_t)row * 320 + col0] = o;
}

// ---------------- pack W: Wp[p][320], p = d*512 + j*4 + g  (gate-interleaved)
__global__ __launch_bounds__(256) void wpack_kernel(const float* __restrict__ Wf,
                                                    const float* __restrict__ Wb,
                                                    u16* __restrict__ Wp) {
  int idx = blockIdx.x * 256 + threadIdx.x;
  int p = idx / 40;
  int c8 = idx - p * 40;
  int col0 = c8 * 8;
  int dd = p >> 9, q = p & 511;
  int j = q >> 2, g = q & 3;
  const float* src = (dd ? Wb : Wf) + (size_t)(g * 128 + j) * 300;
  short8 o;
  #pragma unroll
  for (int e = 0; e < 8; ++e)
    o[e] = (col0 + e < 300) ? (short)f2bf(src[col0 + e]) : (short)0;
  *(short8*)&Wp[(size_t)p * 320 + col0] = o;
}

// ---------------- GEMM: G[65536][1024] bf16 = A @ Wp^T + bias (gate-interleaved cols)
__global__ __launch_bounds__(256) void gemm_kernel(const u16* __restrict__ A,
                                                   const u16* __restrict__ B,
                                                   const float* __restrict__ bf_,
                                                   const float* __restrict__ bb_,
                                                   u16* __restrict__ G) {
  __shared__ u16 At[128 * 32];
  __shared__ u16 Bt[128 * 32];
  const int n = blockIdx.x;
  const int xcd = n & 7, rr = n >> 3;
  const int bx = xcd * 64 + (rr >> 3);
  const int by = rr & 7;
  const int tid = threadIdx.x;
  const int lane = tid & 63;
  const int wave = tid >> 6;
  const int wr = wave >> 1, wc = wave & 1;
  const int arow0 = bx * 128;
  const int bcol0 = by * 128;
  floatx4 acc[4][4] = {};
  const int fq = lane >> 4;
  const int fr = lane & 15;
  const int sr = wave * 32 + (lane >> 2);
  const int sc = (lane & 3) * 8;
  for (int k0 = 0; k0 < 320; k0 += 32) {
    #pragma unroll
    for (int q = 0; q < 2; ++q) {
      gload_lds16(&A[(size_t)(arow0 + sr + q * 16) * 320 + k0 + sc], &At[wave * 1024 + q * 512]);
      gload_lds16(&B[(size_t)(bcol0 + sr + q * 16) * 320 + k0 + sc], &Bt[wave * 1024 + q * 512]);
    }
    __syncthreads();
    short8 af[4], bfr[4];
    #pragma unroll
    for (int mi = 0; mi < 4; ++mi)
      af[mi] = *(const short8*)&At[(wr * 64 + mi * 16 + fr) * 32 + fq * 8];
    #pragma unroll
    for (int ni = 0; ni < 4; ++ni)
      bfr[ni] = *(const short8*)&Bt[(wc * 64 + ni * 16 + fr) * 32 + fq * 8];
    #pragma unroll
    for (int mi = 0; mi < 4; ++mi)
      #pragma unroll
      for (int ni = 0; ni < 4; ++ni)
        acc[mi][ni] = __builtin_amdgcn_mfma_f32_16x16x32_bf16(af[mi], bfr[ni], acc[mi][ni], 0, 0, 0);
    __syncthreads();
  }
  float biasv[4];
  #pragma unroll
  for (int ni = 0; ni < 4; ++ni) {
    int col = bcol0 + wc * 64 + ni * 16 + fr;
    int dd = col >> 9, q = col & 511;
    int jj = q >> 2, gg = q & 3;
    biasv[ni] = (dd ? bb_ : bf_)[gg * 128 + jj];
  }
  #pragma unroll
  for (int mi = 0; mi < 4; ++mi)
    #pragma unroll
    for (int ni = 0; ni < 4; ++ni)
      #pragma unroll
      for (int r = 0; r < 4; ++r) {
        int row = arow0 + wr * 64 + mi * 16 + fq * 4 + r;
        int col = bcol0 + wc * 64 + ni * 16 + fr;
        G[(size_t)row * 1024 + col] = f2bf(acc[mi][ni][r] + biasv[ni]);
      }
}

// ---------------- MFMA LSTM with act-exchange: 64 WGs = (dir 2) x (batch-grp 32 of 4).
// Gate-interleaved packed rows p=j*4+g: wave w's tile tt covers p in [64w+16tt,+16);
// lane (fq,fr): D rows 4fq+r -> (j=16w+4tt+fq, gate=r, b=fr). Phase 1: MFMA + dump
// gate-quads (fr<4) to LDS. Phase 2: 512 threads x 1 element each -> trans/lane 28->7.
__global__ __launch_bounds__(512, 2) void lstm_xch_kernel(const u16* __restrict__ Gp,
                                                          const float* __restrict__ Whh_f,
                                                          const float* __restrict__ Whh_b,
                                                          u16* __restrict__ hs) {
  const int bid = blockIdx.x;
  const int d  = bid >> 5;
  const int b0 = (bid & 31) * 4;
  const int tid = threadIdx.x;
  const int w = tid >> 6, lane = tid & 63;
  const int fr = lane & 15, fq = lane >> 4;
  const float* Wd = d ? Whh_b : Whh_f;

  // A-frags of packed Whh: Wfr[tt][kk]; lane holds packed row p = 64w+16tt+fr,
  // k = fq*8 + kk*32 (+e). Orig row = (p&3)*128 + (p>>2).
  short8 Wfr[4][4];
  #pragma unroll
  for (int tt = 0; tt < 4; ++tt) {
    const int orow = (fr & 3) * 128 + (16 * w + 4 * tt + (fr >> 2));
    #pragma unroll
    for (int kk = 0; kk < 4; ++kk) {
      const float* src = Wd + (size_t)orow * 128 + fq * 8 + kk * 32;
      float4 x0 = *(const float4*)src;
      float4 x1 = *(const float4*)(src + 4);
      short8 o;
      o[0] = (short)f2bf(x0.x); o[1] = (short)f2bf(x0.y);
      o[2] = (short)f2bf(x0.z); o[3] = (short)f2bf(x0.w);
      o[4] = (short)f2bf(x1.x); o[5] = (short)f2bf(x1.y);
      o[6] = (short)f2bf(x1.z); o[7] = (short)f2bf(x1.w);
      Wfr[tt][kk] = o;
    }
  }

  __shared__ __align__(16) u16 hbuf[16 * 136];      // [b][j], rows b>=4 stay 0
  __shared__ __align__(16) float pre[4 * 520];      // [b][j*4+g], row stride 520 f32
  for (int i = tid; i < 16 * 136; i += 512) hbuf[i] = 0;
  __syncthreads();

  const int ts = d ? -1 : 1;
  const int t0 = d ? 511 : 0;
  const int bb = tid >> 7;          // phase-2 element: batch 0..3
  const int jj = tid & 127;         //                  j 0..127
  float cst = 0.f;                  // cell state of (bb, jj)

  const int hoff_r = fr * 136 + fq * 8;
  const int preW0  = fr * 520 + (16 * w + fq) * 4;  // + 16*tt per tile
  const int preR   = bb * 520 + jj * 4;
  const int hwadr  = bb * 136 + jj;
  const long long gstep = (long long)ts * 131072;
  const long long hstep = (long long)ts * 256;
  const u16* gld = Gp + (long long)t0 * 131072 + (b0 + bb) * 1024 + d * 512 + 4 * jj;
  u16* hsp = hs + (size_t)(b0 + bb) * 131072 + (long long)t0 * 256 + d * 128 + jj;

  uint2 gA, gB, gC;
  gA = *(const uint2*)gld; gld += gstep;
  gB = *(const uint2*)gld; gld += gstep;
  gC = *(const uint2*)gld; gld += gstep;

#define STEPX(GB_, PF_) { \
    /* phase 1: h -> preacts */ \
    short8 f0 = *(const short8*)(hbuf + hoff_r); \
    short8 f1 = *(const short8*)(hbuf + hoff_r + 32); \
    short8 f2 = *(const short8*)(hbuf + hoff_r + 64); \
    short8 f3 = *(const short8*)(hbuf + hoff_r + 96); \
    floatx4 a0 = {0.f, 0.f, 0.f, 0.f}; \
    floatx4 a1 = a0, a2 = a0, a3 = a0; \
    a0 = __builtin_amdgcn_mfma_f32_16x16x32_bf16(Wfr[0][0], f0, a0, 0, 0, 0); \
    a1 = __builtin_amdgcn_mfma_f32_16x16x32_bf16(Wfr[1][0], f0, a1, 0, 0, 0); \
    a2 = __builtin_amdgcn_mfma_f32_16x16x32_bf16(Wfr[2][0], f0, a2, 0, 0, 0); \
    a3 = __builtin_amdgcn_mfma_f32_16x16x32_bf16(Wfr[3][0], f0, a3, 0, 0, 0); \
    a0 = __builtin_amdgcn_mfma_f32_16x16x32_bf16(Wfr[0][1], f1, a0, 0, 0, 0); \
    a1 = __builtin_amdgcn_mfma_f32_16x16x32_bf16(Wfr[1][1], f1, a1, 0, 0, 0); \
    a2 = __builtin_amdgcn_mfma_f32_16x16x32_bf16(Wfr[2][1], f1, a2, 0, 0, 0); \
    a3 = __builtin_amdgcn_mfma_f32_16x16x32_bf16(Wfr[3][1], f1, a3, 0, 0, 0); \
    a0 = __builtin_amdgcn_mfma_f32_16x16x32_bf16(Wfr[0][2], f2, a0, 0, 0, 0); \
    a1 = __builtin_amdgcn_mfma_f32_16x16x32_bf16(Wfr[1][2], f2, a1, 0, 0, 0); \
    a2 = __builtin_amdgcn_mfma_f32_16x16x32_bf16(Wfr[2][2], f2, a2, 0, 0, 0); \
    a3 = __builtin_amdgcn_mfma_f32_16x16x32_bf16(Wfr[3][2], f2, a3, 0, 0, 0); \
    a0 = __builtin_amdgcn_mfma_f32_16x16x32_bf16(Wfr[0][3], f3, a0, 0, 0, 0); \
    a1 = __builtin_amdgcn_mfma_f32_16x16x32_bf16(Wfr[1][3], f3, a1, 0, 0, 0); \
    a2 = __builtin_amdgcn_mfma_f32_16x16x32_bf16(Wfr[2][3], f3, a2, 0, 0, 0); \
    a3 = __builtin_amdgcn_mfma_f32_16x16x32_bf16(Wfr[3][3], f3, a3, 0, 0, 0); \
    if (fr < 4) { \
      *(float4*)(pre + preW0)      = *(float4*)&a0; \
      *(float4*)(pre + preW0 + 16) = *(float4*)&a1; \
      *(float4*)(pre + preW0 + 32) = *(float4*)&a2; \
      *(float4*)(pre + preW0 + 48) = *(float4*)&a3; \
    } \
    __builtin_amdgcn_sched_barrier(0); \
    asm volatile("s_waitcnt lgkmcnt(0)"); \
    __builtin_amdgcn_sched_barrier(0); \
    __builtin_amdgcn_s_barrier(); \
    __builtin_amdgcn_sched_barrier(0); \
    /* phase 2: 1 element per thread */ \
    float4 pv = *(const float4*)(pre + preR); \
    float G0 = __builtin_bit_cast(float, GB_.x << 16); \
    float G1 = __builtin_bit_cast(float, GB_.x & 0xffff0000u); \
    float G2 = __builtin_bit_cast(float, GB_.y << 16); \
    float G3 = __builtin_bit_cast(float, GB_.y & 0xffff0000u); \
    if (PF_) { GB_ = *(const uint2*)gld; gld += gstep; } \
    float i_ = pv.x + G0, f_ = pv.y + G1, g_ = pv.z + G2, o_ = pv.w + G3; \
    float p  = __builtin_amdgcn_exp2f(__builtin_amdgcn_fmed3f(g_ * TWOLOG2E, -40.f, 40.f)); \
    float qi = __builtin_amdgcn_exp2f(__builtin_amdgcn_fmed3f(i_ * -LOG2E, -40.f, 40.f)); \
    float qf = __builtin_amdgcn_exp2f(__builtin_amdgcn_fmed3f(f_ * -LOG2E, -40.f, 40.f)); \
    float qo = __builtin_amdgcn_exp2f(__builtin_amdgcn_fmed3f(o_ * -LOG2E, -40.f, 40.f)); \
    float D1 = (1.f + qi) * (p + 1.f); \
    float qf1 = 1.f + qf; \
    float cn = (cst * D1 + (p - 1.f) * qf1) * __builtin_amdgcn_rcpf(qf1 * D1); \
    cst = cn; \
    float v = __builtin_amdgcn_exp2f(__builtin_amdgcn_fmed3f(cn * TWOLOG2E, -40.f, 40.f)); \
    float h = (v - 1.f) * __builtin_amdgcn_rcpf((1.f + qo) * (v + 1.f)); \
    u16 hb = f2bf(h); \
    hbuf[hwadr] = hb; \
    *hsp = hb; \
    hsp += hstep; \
    __builtin_amdgcn_sched_barrier(0); \
    asm volatile("s_waitcnt lgkmcnt(0)"); \
    __builtin_amdgcn_sched_barrier(0); \
    __builtin_amdgcn_s_barrier(); \
    __builtin_amdgcn_sched_barrier(0); \
  }

  #pragma unroll 1
  for (int s = 0; s < 510; s += 3) {
    STEPX(gA, true);
    STEPX(gB, true);
    STEPX(gC, true);
  }
  STEPX(gA, false);
  STEPX(gB, false);
#undef STEPX
}

// ---------------- emissions: y[65536][12] = hs(bf16)[65536][256] @ Wout^T + bout
__global__ __launch_bounds__(256) void emis_kernel(const u16* __restrict__ hs,
                                                   const float* __restrict__ Wout,
                                                   const float* __restrict__ bout,
                                                   float* __restrict__ y) {
  __shared__ float Ws[12 * 256];
  __shared__ float bs[12];
  const int tid = threadIdx.x;
  for (int i = tid; i < 12 * 256; i += 256) Ws[i] = Wout[i];
  if (tid < 12) bs[tid] = bout[tid];
  __syncthreads();
  const int wave = tid >> 6, lane = tid & 63;
  const size_t m = (size_t)blockIdx.x * 4 + wave;
  uint2 hv = *(const uint2*)&hs[m * 256 + lane * 4];
  float h0 = __builtin_bit_cast(float, hv.x << 16);
  float h1 = __builtin_bit_cast(float, hv.x & 0xffff0000u);
  float h2 = __builtin_bit_cast(float, hv.y << 16);
  float h3 = __builtin_bit_cast(float, hv.y & 0xffff0000u);
  float p[12];
  #pragma unroll
  for (int tg = 0; tg < 12; ++tg) {
    const float* wv = &Ws[tg * 256 + lane * 4];
    p[tg] = h0 * wv[0] + h1 * wv[1] + h2 * wv[2] + h3 * wv[3];
  }
  #pragma unroll
  for (int off = 32; off; off >>= 1)
    #pragma unroll
    for (int tg = 0; tg < 12; ++tg)
      p[tg] += __shfl_xor(p[tg], off);
  if (lane == 0) {
    #pragma unroll
    for (int tg = 0; tg < 12; ++tg)
      y[m * 12 + tg] = p[tg] + bs[tg];
  }
}

// ---------------- CRF: forward Z + gold score, one wave per batch (lane-0 normalized)
__global__ __launch_bounds__(64) void crf_kernel(const float* __restrict__ y,
                                                 const int* __restrict__ y0,
                                                 const float* __restrict__ trans,
                                                 float* __restrict__ out) {
  const int b = blockIdx.x;
  const int lane = threadIdx.x;
  __shared__ float trs[144];
  for (int i = lane; i < 144; i += 64) trs[i] = trans[i];
  __syncthreads();
  float etr[12];
  #pragma unroll
  for (int jj = 0; jj < 12; ++jj) etr[jj] = 0.f;
  float z = NEGV, treos = 0.f;
  if (lane < 12) {
    #pragma unroll
    for (int jj = 0; jj < 12; ++jj) etr[jj] = __expf(trs[lane * 12 + jj]);
    z = (lane == SOS) ? 0.f : NEGV;
    treos = trs[EOS * 12 + lane];
  }
  float base = 0.f;
  const float* yb = y + (size_t)b * 512 * 12;
  float e0 = (lane < 12) ? yb[lane] : 0.f;
  float e1 = (lane < 12) ? yb[12 + lane] : 0.f;
  for (int t = 0; t < 512; ++t) {
    float emit = e0;
    e0 = e1;
    if (t + 2 < 512 && lane < 12) e1 = yb[(t + 2) * 12 + lane];
    float zj[12];
    #pragma unroll
    for (int jj = 0; jj < 12; ++jj) zj[jj] = __shfl(z, jj);
    float l = 0.f;
    if (lane < 12) {
      float ex[12];
      #pragma unroll
      for (int jj = 0; jj < 12; ++jj) ex[jj] = __expf(zj[jj]) * etr[jj];
      float sum = (((ex[0] + ex[1]) + (ex[2] + ex[3])) + ((ex[4] + ex[5]) + (ex[6] + ex[7])))
                + ((ex[8] + ex[9]) + (ex[10] + ex[11]));
      l = __logf(sum) + emit;
    }
    float l0 = __shfl(l, 0);
    z = l - l0;
    base += l0;
  }
  float v = (lane < 12) ? z + treos : -INFINITY;
  float M2 = v;
  #pragma unroll
  for (int off = 32; off; off >>= 1) M2 = fmaxf(M2, __shfl_xor(M2, off));
  float e = __expf(v - M2);
  #pragma unroll
  for (int off = 32; off; off >>= 1) e += __shfl_xor(e, off);
  const float Z = base + M2 + __logf(e);
  const int* y0b = y0 + (size_t)b * 512;
  float acc = 0.f;
  for (int t = lane; t < 512; t += 64) {
    int cur = y0b[t];
    int prev = t ? y0b[t - 1] : SOS;
    acc += yb[t * 12 + cur] + trs[cur * 12 + prev];
  }
  #pragma unroll
  for (int off = 32; off; off >>= 1) acc += __shfl_xor(acc, off);
  if (lane == 0) {
    float gold = acc + trs[EOS * 12 + y0b[511]];
    out[b] = Z - gold;
  }
}

extern "C" void kernel_launch(void* const* d_in, const int* in_sizes, int n_in,
                              void* d_out, int out_size, void* d_ws, size_t ws_size,
                              hipStream_t stream) {
  (void)in_sizes; (void)n_in; (void)out_size; (void)ws_size;
  const int*   x     = (const int*)d_in[0];
  const int*   y0    = (const int*)d_in[1];
  const float* embed = (const float*)d_in[2];
  const float* Wih_f = (const float*)d_in[3];
  const float* Whh_f = (const float*)d_in[4];
  const float* b_f   = (const float*)d_in[5];
  const float* Wih_b = (const float*)d_in[6];
  const float* Whh_b = (const float*)d_in[7];
  const float* b_b   = (const float*)d_in[8];
  const float* Wout  = (const float*)d_in[9];
  const float* bout  = (const float*)d_in[10];
  const float* trans = (const float*)d_in[11];
  float* out = (float*)d_out;

  char* ws = (char*)d_ws;
  u16*   A  = (u16*)(ws);                      // 65536*320 bf16  = 41,943,040 B
  u16*   Wp = (u16*)(ws + 41943040);           // 1024*320  bf16  =    655,360 B
  u16*   G  = (u16*)(ws + 42598400);           // 65536*1024 bf16 = 134,217,728 B
  u16*   hs = (u16*)(ws + 176816128);          // 65536*256 bf16  =  33,554,432 B
  float* yy = (float*)(ws + 210370560);        // 65536*12  f32   =   3,145,728 B

  gather_kernel<<<10240, 256, 0, stream>>>(embed, x, A);
  wpack_kernel<<<160, 256, 0, stream>>>(Wih_f, Wih_b, Wp);
  gemm_kernel<<<4096, 256, 0, stream>>>(A, Wp, b_f, b_b, G);
  lstm_xch_kernel<<<64, 512, 0, stream>>>(G, Whh_f, Whh_b, hs);
  emis_kernel<<<16384, 256, 0, stream>>>(hs, Wout, bout, yy);
  crf_kernel<<<128, 64, 0, stream>>>(yy, y0, trans, out);
}

// Round 7
// 678.936 us; speedup vs baseline: 2.0514x; 1.0013x over previous
//
#include <hip/hip_runtime.h>

typedef unsigned short u16;
typedef __attribute__((ext_vector_type(8))) short short8;
typedef __attribute__((ext_vector_type(4))) float floatx4;

#define SOS 3
#define EOS 4
#define NEGV -10000.0f
#define LOG2E 1.442695041f
#define TWOLOG2E 2.885390082f

__device__ __forceinline__ u16 f2bf(float f) {
  union { float f; unsigned int i; } v; v.f = f;
  unsigned int r = (v.i + 0x7FFFu + ((v.i >> 16) & 1u)) >> 16;
  return (u16)r;
}
__device__ __forceinline__ void gload_lds16(const u16* g, u16* l) {
  __builtin_amdgcn_global_load_lds((const __attribute__((address_space(1))) void*)g,
                                   (__attribute__((address_space(3))) void*)l, 16, 0, 0);
}

// ---------------- gather: A[m=t*128+b][320] bf16 = embed[x[b][t]][k], zero-pad k>=300
__global__ __launch_bounds__(256) void gather_kernel(const float* __restrict__ embed,
                                                     const int* __restrict__ x,
                                                     u16* __restrict__ A) {
  int idx = blockIdx.x * 256 + threadIdx.x;
  int row = idx / 40;
  int c8 = idx - row * 40;
  int col0 = c8 * 8;
  int b = row & 127, t = row >> 7;
  const float* src = embed + (size_t)x[b * 512 + t] * 300 + col0;
  short8 o;
  if (col0 + 8 <= 300) {
    float4 f0 = *(const float4*)(src);
    float4 f1 = *(const float4*)(src + 4);
    o[0] = (short)f2bf(f0.x); o[1] = (short)f2bf(f0.y);
    o[2] = (short)f2bf(f0.z); o[3] = (short)f2bf(f0.w);
    o[4] = (short)f2bf(f1.x); o[5] = (short)f2bf(f1.y);
    o[6] = (short)f2bf(f1.z); o[7] = (short)f2bf(f1.w);
  } else {
    #pragma unroll
    for (int e = 0; e < 8; ++e)
      o[e] = (col0 + e < 300) ? (short)f2bf(src[e]) : (short)0;
  }
  *(short8*)&A[(size_t)row * 320 + col0] = o;
}

// ---------------- pack W: Wp[p][320], p = d*512 + j*4 + g  (gate-interleaved)
__global__ __launch_bounds__(256) void wpack_kernel(const float* __restrict__ Wf,
                                                    const float* __restrict__ Wb,
                                                    u16* __restrict__ Wp) {
  int idx = blockIdx.x * 256 + threadIdx.x;
  int p = idx / 40;
  int c8 = idx - p * 40;
  int col0 = c8 * 8;
  int dd = p >> 9, q = p & 511;
  int j = q >> 2, g = q & 3;
  const float* src = (dd ? Wb : Wf) + (size_t)(g * 128 + j) * 300;
  short8 o;
  #pragma unroll
  for (int e = 0; e < 8; ++e)
    o[e] = (col0 + e < 300) ? (short)f2bf(src[col0 + e]) : (short)0;
  *(short8*)&Wp[(size_t)p * 320 + col0] = o;
}

// ---------------- GEMM: G[65536][1024] bf16 = A @ Wp^T + bias (gate-interleaved cols)
__global__ __launch_bounds__(256) void gemm_kernel(const u16* __restrict__ A,
                                                   const u16* __restrict__ B,
                                                   const float* __restrict__ bf_,
                                                   const float* __restrict__ bb_,
                                                   u16* __restrict__ G) {
  __shared__ u16 At[128 * 32];
  __shared__ u16 Bt[128 * 32];
  const int n = blockIdx.x;
  const int xcd = n & 7, rr = n >> 3;
  const int bx = xcd * 64 + (rr >> 3);
  const int by = rr & 7;
  const int tid = threadIdx.x;
  const int lane = tid & 63;
  const int wave = tid >> 6;
  const int wr = wave >> 1, wc = wave & 1;
  const int arow0 = bx * 128;
  const int bcol0 = by * 128;
  floatx4 acc[4][4] = {};
  const int fq = lane >> 4;
  const int fr = lane & 15;
  const int sr = wave * 32 + (lane >> 2);
  const int sc = (lane & 3) * 8;
  for (int k0 = 0; k0 < 320; k0 += 32) {
    #pragma unroll
    for (int q = 0; q < 2; ++q) {
      gload_lds16(&A[(size_t)(arow0 + sr + q * 16) * 320 + k0 + sc], &At[wave * 1024 + q * 512]);
      gload_lds16(&B[(size_t)(bcol0 + sr + q * 16) * 320 + k0 + sc], &Bt[wave * 1024 + q * 512]);
    }
    __syncthreads();
    short8 af[4], bfr[4];
    #pragma unroll
    for (int mi = 0; mi < 4; ++mi)
      af[mi] = *(const short8*)&At[(wr * 64 + mi * 16 + fr) * 32 + fq * 8];
    #pragma unroll
    for (int ni = 0; ni < 4; ++ni)
      bfr[ni] = *(const short8*)&Bt[(wc * 64 + ni * 16 + fr) * 32 + fq * 8];
    #pragma unroll
    for (int mi = 0; mi < 4; ++mi)
      #pragma unroll
      for (int ni = 0; ni < 4; ++ni)
        acc[mi][ni] = __builtin_amdgcn_mfma_f32_16x16x32_bf16(af[mi], bfr[ni], acc[mi][ni], 0, 0, 0);
    __syncthreads();
  }
  float biasv[4];
  #pragma unroll
  for (int ni = 0; ni < 4; ++ni) {
    int col = bcol0 + wc * 64 + ni * 16 + fr;
    int dd = col >> 9, q = col & 511;
    int jj = q >> 2, gg = q & 3;
    biasv[ni] = (dd ? bb_ : bf_)[gg * 128 + jj];
  }
  #pragma unroll
  for (int mi = 0; mi < 4; ++mi)
    #pragma unroll
    for (int ni = 0; ni < 4; ++ni)
      #pragma unroll
      for (int r = 0; r < 4; ++r) {
        int row = arow0 + wr * 64 + mi * 16 + fq * 4 + r;
        int col = bcol0 + wc * 64 + ni * 16 + fr;
        G[(size_t)row * 1024 + col] = f2bf(acc[mi][ni][r] + biasv[ni]);
      }
}

// ---------------- MFMA LSTM with act-exchange, conflict-free LDS (XOR-swizzled).
// 64 WGs = (dir 2) x (batch-grp 32 of 4). Phase 1: MFMA j*4+g packed rows, dump
// gate-quads to pre[]; Phase 2: 512 threads x 1 element. hbuf chunk-swizzled
// (chunk ^ (b&7)); pre slot-swizzled (j ^ ((j>>3)&7), row stride 130).
__global__ __launch_bounds__(512, 2) void lstm_xch_kernel(const u16* __restrict__ Gp,
                                                          const float* __restrict__ Whh_f,
                                                          const float* __restrict__ Whh_b,
                                                          u16* __restrict__ hs) {
  const int bid = blockIdx.x;
  const int d  = bid >> 5;
  const int b0 = (bid & 31) * 4;
  const int tid = threadIdx.x;
  const int w = tid >> 6, lane = tid & 63;
  const int fr = lane & 15, fq = lane >> 4;
  const float* Wd = d ? Whh_b : Whh_f;

  // A-frags of packed Whh: Wfr[tt][kk]; packed row p = 64w+16tt+fr -> orig (fr&3)*128 + j
  short8 Wfr[4][4];
  #pragma unroll
  for (int tt = 0; tt < 4; ++tt) {
    const int orow = (fr & 3) * 128 + (16 * w + 4 * tt + (fr >> 2));
    #pragma unroll
    for (int kk = 0; kk < 4; ++kk) {
      const float* src = Wd + (size_t)orow * 128 + fq * 8 + kk * 32;
      float4 x0 = *(const float4*)src;
      float4 x1 = *(const float4*)(src + 4);
      short8 o;
      o[0] = (short)f2bf(x0.x); o[1] = (short)f2bf(x0.y);
      o[2] = (short)f2bf(x0.z); o[3] = (short)f2bf(x0.w);
      o[4] = (short)f2bf(x1.x); o[5] = (short)f2bf(x1.y);
      o[6] = (short)f2bf(x1.z); o[7] = (short)f2bf(x1.w);
      Wfr[tt][kk] = o;
    }
  }

  __shared__ __align__(16) u16 hbuf[16 * 128];     // (b,j) -> b*128 + ((j>>3 ^ (b&7))<<3) + (j&7)
  __shared__ __align__(16) float pre[4 * 130 * 4]; // (b,j) quad -> slot b*130 + (j ^ ((j>>3)&7))
  for (int i = tid; i < 16 * 128; i += 512) hbuf[i] = 0;
  __syncthreads();

  const int ts = d ? -1 : 1;
  const int t0 = d ? 511 : 0;
  const int bb = tid >> 7;          // phase-2 element: batch 0..3
  const int jj = tid & 127;         //                  j 0..127
  float cst = 0.f;

  // P1 hbuf read bases (chunk = fq + 4kk, row fr)
  const int sx = fr & 7;
  const int ho0 = fr * 128 + (((fq)      ^ sx) << 3);
  const int ho1 = fr * 128 + (((fq + 4)  ^ sx) << 3);
  const int ho2 = fr * 128 + (((fq + 8)  ^ sx) << 3);
  const int ho3 = fr * 128 + (((fq + 12) ^ sx) << 3);
  // P1 pre write bases (float index), valid when fr<4
  int pw[4];
  #pragma unroll
  for (int tt = 0; tt < 4; ++tt) {
    const int jjw = 16 * w + 4 * tt + fq;
    pw[tt] = (fr * 130 + (jjw ^ ((jjw >> 3) & 7))) * 4;
  }
  const int pw0 = pw[0], pw1 = pw[1], pw2 = pw[2], pw3 = pw[3];
  const bool wr_pre = (fr < 4);
  // P2 addresses
  const int pr = (bb * 130 + (jj ^ ((jj >> 3) & 7))) * 4;
  const int hw = bb * 128 + ((((jj >> 3) ^ (bb & 7))) << 3) + (jj & 7);

  const long long gstep = (long long)ts * 131072;
  const long long hstep = (long long)ts * 256;
  const u16* gld = Gp + (long long)t0 * 131072 + (b0 + bb) * 1024 + d * 512 + 4 * jj;
  u16* hsp = hs + (size_t)(b0 + bb) * 131072 + (long long)t0 * 256 + d * 128 + jj;

  uint2 gA, gB, gC;
  gA = *(const uint2*)gld; gld += gstep;
  gB = *(const uint2*)gld; gld += gstep;
  gC = *(const uint2*)gld; gld += gstep;

#define STEPX(GB_, PF_) { \
    /* phase 1: h -> preacts */ \
    short8 f0 = *(const short8*)(hbuf + ho0); \
    short8 f1 = *(const short8*)(hbuf + ho1); \
    short8 f2 = *(const short8*)(hbuf + ho2); \
    short8 f3 = *(const short8*)(hbuf + ho3); \
    floatx4 a0 = {0.f, 0.f, 0.f, 0.f}; \
    floatx4 a1 = a0, a2 = a0, a3 = a0; \
    a0 = __builtin_amdgcn_mfma_f32_16x16x32_bf16(Wfr[0][0], f0, a0, 0, 0, 0); \
    a1 = __builtin_amdgcn_mfma_f32_16x16x32_bf16(Wfr[1][0], f0, a1, 0, 0, 0); \
    a2 = __builtin_amdgcn_mfma_f32_16x16x32_bf16(Wfr[2][0], f0, a2, 0, 0, 0); \
    a3 = __builtin_amdgcn_mfma_f32_16x16x32_bf16(Wfr[3][0], f0, a3, 0, 0, 0); \
    a0 = __builtin_amdgcn_mfma_f32_16x16x32_bf16(Wfr[0][1], f1, a0, 0, 0, 0); \
    a1 = __builtin_amdgcn_mfma_f32_16x16x32_bf16(Wfr[1][1], f1, a1, 0, 0, 0); \
    a2 = __builtin_amdgcn_mfma_f32_16x16x32_bf16(Wfr[2][1], f1, a2, 0, 0, 0); \
    a3 = __builtin_amdgcn_mfma_f32_16x16x32_bf16(Wfr[3][1], f1, a3, 0, 0, 0); \
    a0 = __builtin_amdgcn_mfma_f32_16x16x32_bf16(Wfr[0][2], f2, a0, 0, 0, 0); \
    a1 = __builtin_amdgcn_mfma_f32_16x16x32_bf16(Wfr[1][2], f2, a1, 0, 0, 0); \
    a2 = __builtin_amdgcn_mfma_f32_16x16x32_bf16(Wfr[2][2], f2, a2, 0, 0, 0); \
    a3 = __builtin_amdgcn_mfma_f32_16x16x32_bf16(Wfr[3][2], f2, a3, 0, 0, 0); \
    a0 = __builtin_amdgcn_mfma_f32_16x16x32_bf16(Wfr[0][3], f3, a0, 0, 0, 0); \
    a1 = __builtin_amdgcn_mfma_f32_16x16x32_bf16(Wfr[1][3], f3, a1, 0, 0, 0); \
    a2 = __builtin_amdgcn_mfma_f32_16x16x32_bf16(Wfr[2][3], f3, a2, 0, 0, 0); \
    a3 = __builtin_amdgcn_mfma_f32_16x16x32_bf16(Wfr[3][3], f3, a3, 0, 0, 0); \
    if (wr_pre) { \
      *(floatx4*)(pre + pw0) = a0; \
      *(floatx4*)(pre + pw1) = a1; \
      *(floatx4*)(pre + pw2) = a2; \
      *(floatx4*)(pre + pw3) = a3; \
    } \
    __builtin_amdgcn_sched_barrier(0); \
    asm volatile("s_waitcnt lgkmcnt(0)"); \
    __builtin_amdgcn_sched_barrier(0); \
    __builtin_amdgcn_s_barrier(); \
    __builtin_amdgcn_sched_barrier(0); \
    /* phase 2: 1 element per thread */ \
    float4 pv = *(const float4*)(pre + pr); \
    float G0 = __builtin_bit_cast(float, GB_.x << 16); \
    float G1 = __builtin_bit_cast(float, GB_.x & 0xffff0000u); \
    float G2 = __builtin_bit_cast(float, GB_.y << 16); \
    float G3 = __builtin_bit_cast(float, GB_.y & 0xffff0000u); \
    if (PF_) { GB_ = *(const uint2*)gld; gld += gstep; } \
    float i_ = pv.x + G0, f_ = pv.y + G1, g_ = pv.z + G2, o_ = pv.w + G3; \
    float p  = __builtin_amdgcn_exp2f(__builtin_amdgcn_fmed3f(g_ * TWOLOG2E, -40.f, 40.f)); \
    float qi = __builtin_amdgcn_exp2f(__builtin_amdgcn_fmed3f(i_ * -LOG2E, -40.f, 40.f)); \
    float qf = __builtin_amdgcn_exp2f(__builtin_amdgcn_fmed3f(f_ * -LOG2E, -40.f, 40.f)); \
    float qo = __builtin_amdgcn_exp2f(__builtin_amdgcn_fmed3f(o_ * -LOG2E, -40.f, 40.f)); \
    float D1 = (1.f + qi) * (p + 1.f); \
    float qf1 = 1.f + qf; \
    float cn = (cst * D1 + (p - 1.f) * qf1) * __builtin_amdgcn_rcpf(qf1 * D1); \
    cst = cn; \
    float v = __builtin_amdgcn_exp2f(__builtin_amdgcn_fmed3f(cn * TWOLOG2E, -40.f, 40.f)); \
    float h = (v - 1.f) * __builtin_amdgcn_rcpf((1.f + qo) * (v + 1.f)); \
    u16 hb = f2bf(h); \
    hbuf[hw] = hb; \
    *hsp = hb; \
    hsp += hstep; \
    __builtin_amdgcn_sched_barrier(0); \
    asm volatile("s_waitcnt lgkmcnt(0)"); \
    __builtin_amdgcn_sched_barrier(0); \
    __builtin_amdgcn_s_barrier(); \
    __builtin_amdgcn_sched_barrier(0); \
  }

  #pragma unroll 1
  for (int s = 0; s < 510; s += 3) {
    STEPX(gA, true);
    STEPX(gB, true);
    STEPX(gC, true);
  }
  STEPX(gA, false);
  STEPX(gB, false);
#undef STEPX
}

// ---------------- emissions: y[65536][12] = hs(bf16)[65536][256] @ Wout^T + bout
__global__ __launch_bounds__(256) void emis_kernel(const u16* __restrict__ hs,
                                                   const float* __restrict__ Wout,
                                                   const float* __restrict__ bout,
                                                   float* __restrict__ y) {
  __shared__ float Ws[12 * 256];
  __shared__ float bs[12];
  const int tid = threadIdx.x;
  for (int i = tid; i < 12 * 256; i += 256) Ws[i] = Wout[i];
  if (tid < 12) bs[tid] = bout[tid];
  __syncthreads();
  const int wave = tid >> 6, lane = tid & 63;
  const size_t m = (size_t)blockIdx.x * 4 + wave;
  uint2 hv = *(const uint2*)&hs[m * 256 + lane * 4];
  float h0 = __builtin_bit_cast(float, hv.x << 16);
  float h1 = __builtin_bit_cast(float, hv.x & 0xffff0000u);
  float h2 = __builtin_bit_cast(float, hv.y << 16);
  float h3 = __builtin_bit_cast(float, hv.y & 0xffff0000u);
  float p[12];
  #pragma unroll
  for (int tg = 0; tg < 12; ++tg) {
    const float* wv = &Ws[tg * 256 + lane * 4];
    p[tg] = h0 * wv[0] + h1 * wv[1] + h2 * wv[2] + h3 * wv[3];
  }
  #pragma unroll
  for (int off = 32; off; off >>= 1)
    #pragma unroll
    for (int tg = 0; tg < 12; ++tg)
      p[tg] += __shfl_xor(p[tg], off);
  if (lane == 0) {
    #pragma unroll
    for (int tg = 0; tg < 12; ++tg)
      y[m * 12 + tg] = p[tg] + bs[tg];
  }
}

// ---------------- CRF: forward Z + gold score, one wave per batch (lane-0 normalized)
__global__ __launch_bounds__(64) void crf_kernel(const float* __restrict__ y,
                                                 const int* __restrict__ y0,
                                                 const float* __restrict__ trans,
                                                 float* __restrict__ out) {
  const int b = blockIdx.x;
  const int lane = threadIdx.x;
  __shared__ float trs[144];
  for (int i = lane; i < 144; i += 64) trs[i] = trans[i];
  __syncthreads();
  float etr[12];
  #pragma unroll
  for (int jj = 0; jj < 12; ++jj) etr[jj] = 0.f;
  float z = NEGV, treos = 0.f;
  if (lane < 12) {
    #pragma unroll
    for (int jj = 0; jj < 12; ++jj) etr[jj] = __expf(trs[lane * 12 + jj]);
    z = (lane == SOS) ? 0.f : NEGV;
    treos = trs[EOS * 12 + lane];
  }
  float base = 0.f;
  const float* yb = y + (size_t)b * 512 * 12;
  float e0 = (lane < 12) ? yb[lane] : 0.f;
  float e1 = (lane < 12) ? yb[12 + lane] : 0.f;
  for (int t = 0; t < 512; ++t) {
    float emit = e0;
    e0 = e1;
    if (t + 2 < 512 && lane < 12) e1 = yb[(t + 2) * 12 + lane];
    float zj[12];
    #pragma unroll
    for (int jj = 0; jj < 12; ++jj) zj[jj] = __shfl(z, jj);
    float l = 0.f;
    if (lane < 12) {
      float ex[12];
      #pragma unroll
      for (int jj = 0; jj < 12; ++jj) ex[jj] = __expf(zj[jj]) * etr[jj];
      float sum = (((ex[0] + ex[1]) + (ex[2] + ex[3])) + ((ex[4] + ex[5]) + (ex[6] + ex[7])))
                + ((ex[8] + ex[9]) + (ex[10] + ex[11]));
      l = __logf(sum) + emit;
    }
    float l0 = __shfl(l, 0);
    z = l - l0;
    base += l0;
  }
  float v = (lane < 12) ? z + treos : -INFINITY;
  float M2 = v;
  #pragma unroll
  for (int off = 32; off; off >>= 1) M2 = fmaxf(M2, __shfl_xor(M2, off));
  float e = __expf(v - M2);
  #pragma unroll
  for (int off = 32; off; off >>= 1) e += __shfl_xor(e, off);
  const float Z = base + M2 + __logf(e);
  const int* y0b = y0 + (size_t)b * 512;
  float acc = 0.f;
  for (int t = lane; t < 512; t += 64) {
    int cur = y0b[t];
    int prev = t ? y0b[t - 1] : SOS;
    acc += yb[t * 12 + cur] + trs[cur * 12 + prev];
  }
  #pragma unroll
  for (int off = 32; off; off >>= 1) acc += __shfl_xor(acc, off);
  if (lane == 0) {
    float gold = acc + trs[EOS * 12 + y0b[511]];
    out[b] = Z - gold;
  }
}

extern "C" void kernel_launch(void* const* d_in, const int* in_sizes, int n_in,
                              void* d_out, int out_size, void* d_ws, size_t ws_size,
                              hipStream_t stream) {
  (void)in_sizes; (void)n_in; (void)out_size; (void)ws_size;
  const int*   x     = (const int*)d_in[0];
  const int*   y0    = (const int*)d_in[1];
  const float* embed = (const float*)d_in[2];
  const float* Wih_f = (const float*)d_in[3];
  const float* Whh_f = (const float*)d_in[4];
  const float* b_f   = (const float*)d_in[5];
  const float* Wih_b = (const float*)d_in[6];
  const float* Whh_b = (const float*)d_in[7];
  const float* b_b   = (const float*)d_in[8];
  const float* Wout  = (const float*)d_in[9];
  const float* bout  = (const float*)d_in[10];
  const float* trans = (const float*)d_in[11];
  float* out = (float*)d_out;

  char* ws = (char*)d_ws;
  u16*   A  = (u16*)(ws);                      // 65536*320 bf16  = 41,943,040 B
  u16*   Wp = (u16*)(ws + 41943040);           // 1024*320  bf16  =    655,360 B
  u16*   G  = (u16*)(ws + 42598400);           // 65536*1024 bf16 = 134,217,728 B
  u16*   hs = (u16*)(ws + 176816128);          // 65536*256 bf16  =  33,554,432 B
  float* yy = (float*)(ws + 210370560);        // 65536*12  f32   =   3,145,728 B

  gather_kernel<<<10240, 256, 0, stream>>>(embed, x, A);
  wpack_kernel<<<160, 256, 0, stream>>>(Wih_f, Wih_b, Wp);
  gemm_kernel<<<4096, 256, 0, stream>>>(A, Wp, b_f, b_b, G);
  lstm_xch_kernel<<<64, 512, 0, stream>>>(G, Whh_f, Whh_b, hs);
  emis_kernel<<<16384, 256, 0, stream>>>(hs, Wout, bout, yy);
  crf_kernel<<<128, 64, 0, stream>>>(yy, y0, trans, out);
}